// Round 3
// baseline (243.697 us; speedup 1.0000x reference)
//
#include <hip/hip_runtime.h>

// 3D spatial transformer (trilinear warp), voxelmorph semantics.
// vol: [B=2, X=160, Y=192, Z=160, C=1] fp32
// trf: [B=2, X=160, Y=192, Z=160, 3]  fp32 (dense displacement)
// out: same shape as vol, fp32.
//
// R7 (= R5 structure + two fixes; R6's z-strided ownership reverted — it
// broke f4 trf/out vectorization and cost +25% WRITE_SIZE):
// (a) staged window 14x22x32 = 38.5 KB -> 4 blocks/CU (was 3) = 32/32 waves.
//     Halo 3 in x,y (fallback ~0.5% of voxels, vol is L3-resident).
// (b) width-4 global_load_lds staging. The 4B granule allows a FULL 5-bit
//     XOR swizzle (slot_z = z ^ yi), so consumer ds_reads spread over all
//     32 banks (~2-way, free). The 16B granule could only permute bank bits
//     2-4 -> structural 8-way conflict (R5's measured 6.2M residual).
//     Staging rows tracked incrementally (no div/mod in the hot loop).

#define NXD 160
#define NYD 192
#define NZD 160
#define NVOX (NXD * NYD * NZD)
#define NBATCH 2

#define TXT 8
#define TYT 16
#define TZT 16
#define LXT 14            // staged x extent (halo 3)
#define LYT 22            // staged y extent (halo 3)
#define LZT 32            // staged z extent (halo 8)
#define NROWS (LXT * LYT)          // 308
#define LDS_N (NROWS * LZT)        // 9856 floats = 38.5 KB

#define TILES_X (NXD / TXT)   // 20
#define TILES_Y (NYD / TYT)   // 12
#define TILES_Z (NZD / TZT)   // 10
#define NBLOCKS (NBATCH * TILES_X * TILES_Y * TILES_Z)   // 4800

typedef float f4 __attribute__((ext_vector_type(4)));

__global__ __launch_bounds__(512, 8)
void warp3d_kernel(const float* __restrict__ vol,
                   const float* __restrict__ trf,
                   float* __restrict__ out) {
    __shared__ float tile[LDS_N];

    int bid = blockIdx.x;
    int tz = bid % TILES_Z;
    int r  = bid / TILES_Z;
    int ty = r % TILES_Y;
    int r2 = r / TILES_Y;
    int tx = r2 % TILES_X;
    int b  = r2 / TILES_X;

    int x0t = tx * TXT, y0t = ty * TYT, z0t = tz * TZT;
    // clamped staging origin: window always fully inside the volume
    int lox = min(max(x0t - 3, 0), NXD - LXT);
    int loy = min(max(y0t - 3, 0), NYD - LYT);
    int loz = min(max(z0t - 8, 0), NZD - LZT);

    const float* vb = vol + (size_t)b * NVOX;

    int t = threadIdx.x;
    // compute-phase voxel quad: 4 z-consecutive voxels per thread (f4 I/O)
    int zq = t & 3;             // 4 z-quads
    int yq = (t >> 2) & 15;     // 16 y
    int xq = t >> 6;            // 8 x (== wave id)
    int x = x0t + xq, y = y0t + yq, zb0 = z0t + zq * 4;
    size_t vox_i = (((size_t)b * NXD + x) * NYD + y) * NZD + zb0;

    // prefetch trf (12 floats = 3 aligned float4) — overlaps staging latency
    const f4* trfv = (const f4*)(trf + vox_i * 3);
    f4 t0 = trfv[0], t1 = trfv[1], t2 = trfv[2];

    // ---- stage vol tile into LDS (width-4 async, full-XOR z swizzle) ----
    // thread -> (zi = t&31, row walks t>>5, t>>5+16, ...). Dest is linear in
    // t (wave-uniform base + lane*4B); source z is inverse-swizzled per lane.
    {
        int zi = t & 31;
        int yi = t >> 5;                 // row 0..15 -> xi=0, yi=row
        int rowoff = yi * NZD;           // xi*(NYD*NZD) + yi*NZD
        const float* gbase = vb + ((size_t)(lox * NYD + loy) * NZD + loz);
#pragma unroll
        for (int it = 0; it < 20; ++it) {
            int row = it * 16 + (t >> 5);
            if (row < NROWS) {           // last iter: waves 0-1 only (uniform)
                const float* g = gbase + rowoff + (zi ^ yi);
                __builtin_amdgcn_global_load_lds(
                    (const __attribute__((address_space(1))) void*)g,
                    (__attribute__((address_space(3))) void*)
                        &tile[(it * 16 + ((t >> 6) << 1)) * LZT],
                    4, 0, 0);
            }
            // advance 16 rows: yi += 16, wrap into next x-plane if needed
            yi += 16;
            int wrap = yi >= LYT;
            rowoff += wrap ? (16 * NZD - LYT * NZD + NYD * NZD) : 16 * NZD;
            if (wrap) yi -= LYT;
        }
    }
    __syncthreads();

    // ---- gather + trilinear blend, 4 voxels ----
    float dxa[4] = {t0.x, t0.w, t1.z, t2.y};
    float dya[4] = {t0.y, t1.x, t1.w, t2.z};
    float dza[4] = {t0.z, t1.y, t2.x, t2.w};

    float res[4];
#pragma unroll
    for (int j = 0; j < 4; ++j) {
        float lx = fminf(fmaxf((float)x + dxa[j], 0.0f), (float)(NXD - 1));
        float ly = fminf(fmaxf((float)y + dya[j], 0.0f), (float)(NYD - 1));
        float lz = fminf(fmaxf((float)(zb0 + j) + dza[j], 0.0f), (float)(NZD - 1));
        float fx = floorf(lx), fy = floorf(ly), fz = floorf(lz);
        int x0 = (int)fx, y0 = (int)fy, z0 = (int)fz;
        // lower-corner weights d1 = loc1 - loc (0 at clamped top border)
        float wx0 = fminf(fx + 1.0f, (float)(NXD - 1)) - lx;
        float wy0 = fminf(fy + 1.0f, (float)(NYD - 1)) - ly;
        float wz0 = fminf(fz + 1.0f, (float)(NZD - 1)) - lz;

        int ix = x0 - lox, iy = y0 - loy, iz = z0 - loz;
        bool ok = ((unsigned)ix <= LXT - 2) & ((unsigned)iy <= LYT - 2) &
                  ((unsigned)iz <= LZT - 2);
        int sx = ok ? ix : 0;            // safe LDS coords when !ok
        int sy = ok ? iy : 0;
        int sv = ok ? iz : 0;

        int base = (sx * LYT + sy) * LZT;
        int A = base + (sv ^ sy);                    // (y0, z0)
        int B = base + ((sv + 1) ^ sy);              // (y0, z1)
        int C = base + LZT + (sv ^ (sy + 1));        // (y1, z0)
        int D = base + LZT + ((sv + 1) ^ (sy + 1));  // (y1, z1)

        float v000 = tile[A],              v001 = tile[B];
        float v010 = tile[C],              v011 = tile[D];
        float v100 = tile[A + LYT * LZT],  v101 = tile[B + LYT * LZT];
        float v110 = tile[C + LYT * LZT],  v111 = tile[D + LYT * LZT];

        if (!ok) {   // rare: sample outside staged window -> global gather
            int x1 = min(x0 + 1, NXD - 1);
            int y1 = min(y0 + 1, NYD - 1);
            int z1 = min(z0 + 1, NZD - 1);
            size_t o00 = (size_t)(x0 * NYD + y0) * NZD;
            size_t o01 = (size_t)(x0 * NYD + y1) * NZD;
            size_t o10 = (size_t)(x1 * NYD + y0) * NZD;
            size_t o11 = (size_t)(x1 * NYD + y1) * NZD;
            v000 = vb[o00 + z0]; v001 = vb[o00 + z1];
            v010 = vb[o01 + z0]; v011 = vb[o01 + z1];
            v100 = vb[o10 + z0]; v101 = vb[o10 + z1];
            v110 = vb[o11 + z0]; v111 = vb[o11 + z1];
        }

        float wx1 = 1.0f - wx0, wy1 = 1.0f - wy0, wz1 = 1.0f - wz0;
        res[j] = wx0 * (wy0 * (wz0 * v000 + wz1 * v001) +
                        wy1 * (wz0 * v010 + wz1 * v011)) +
                 wx1 * (wy0 * (wz0 * v100 + wz1 * v101) +
                        wy1 * (wz0 * v110 + wz1 * v111));
    }

    f4 o;
    o.x = res[0]; o.y = res[1]; o.z = res[2]; o.w = res[3];
    *(f4*)(out + vox_i) = o;
}

extern "C" void kernel_launch(void* const* d_in, const int* in_sizes, int n_in,
                              void* d_out, int out_size, void* d_ws, size_t ws_size,
                              hipStream_t stream) {
    const float* vol = (const float*)d_in[0];
    const float* trf = (const float*)d_in[1];
    float* out = (float*)d_out;

    warp3d_kernel<<<NBLOCKS, 512, 0, stream>>>(vol, trf, out);
}

// Round 4
// 222.077 us; speedup vs baseline: 1.0974x; 1.0974x over previous
//
#include <hip/hip_runtime.h>

// 3D spatial transformer (trilinear warp), voxelmorph semantics.
// vol: [B=2, X=160, Y=192, Z=160, C=1] fp32
// trf: [B=2, X=160, Y=192, Z=160, 3]  fp32 (dense displacement)
// out: same shape as vol, fp32.
//
// R8 = R5 structure (proven 77.8us, 40 VGPR) + R7's occupancy gain (proven
// 78% occ) MINUS R7's poison (launch_bounds(512,8) forced a 64-VGPR cap ->
// 9 dwords/thread scratch spill -> +86MB WRITE, +42MB FETCH, 100us).
// (a) staged window 14x22x32 = 38.5 KB -> 4 blocks/CU, NO min-wave clause
//     (40 VGPR <= 64 gives 8 waves/SIMD naturally).
// (b) 16B global_load_lds staging with bits-2-4 z-XOR swizzle (R5). The
//     residual ~6M bank-conflict is floor-jitter-random; accepted.
// (c) chunked XCD swizzle (4800%8==0, bijective): tz/ty-neighbor tiles land
//     on the same XCD -> halo + trf L2 reuse.

#define NXD 160
#define NYD 192
#define NZD 160
#define NVOX (NXD * NYD * NZD)
#define NBATCH 2

#define TXT 8
#define TYT 16
#define TZT 16
#define LXT 14            // staged x extent (halo 3)
#define LYT 22            // staged y extent (halo 3)
#define LZT 32            // staged z extent (halo 8)
#define NROWS (LXT * LYT)          // 308 z-rows
#define LDS_N (NROWS * LZT)        // 9856 floats = 38.5 KB
#define NSLOT (NROWS * 8)          // 2464 16B staging slots

#define TILES_X (NXD / TXT)   // 20
#define TILES_Y (NYD / TYT)   // 12
#define TILES_Z (NZD / TZT)   // 10
#define NBLOCKS (NBATCH * TILES_X * TILES_Y * TILES_Z)   // 4800

typedef float f4 __attribute__((ext_vector_type(4)));

__global__ __launch_bounds__(512)
void warp3d_kernel(const float* __restrict__ vol,
                   const float* __restrict__ trf,
                   float* __restrict__ out) {
    __shared__ float tile[LDS_N];

    // chunked XCD swizzle: each XCD gets a contiguous run of 600 tiles
    int bid0 = blockIdx.x;
    int bid = (bid0 & 7) * (NBLOCKS / 8) + (bid0 >> 3);

    int tz = bid % TILES_Z;
    int r  = bid / TILES_Z;
    int ty = r % TILES_Y;
    int r2 = r / TILES_Y;
    int tx = r2 % TILES_X;
    int b  = r2 / TILES_X;

    int x0t = tx * TXT, y0t = ty * TYT, z0t = tz * TZT;
    // clamped staging origin: window always fully inside the volume
    int lox = min(max(x0t - 3, 0), NXD - LXT);
    int loy = min(max(y0t - 3, 0), NYD - LYT);
    int loz = min(max(z0t - 8, 0), NZD - LZT);

    const float* vb = vol + (size_t)b * NVOX;

    int t = threadIdx.x;
    // compute-phase voxel quad: 4 z-consecutive voxels per thread (f4 I/O)
    int zq = t & 3;             // 4 z-quads
    int yq = (t >> 2) & 15;     // 16 y
    int xq = t >> 6;            // 8 x (== wave id)
    int x = x0t + xq, y = y0t + yq, zb0 = z0t + zq * 4;
    size_t vox_i = (((size_t)b * NXD + x) * NYD + y) * NZD + zb0;

    // prefetch trf (12 floats = 3 aligned float4) — overlaps staging latency
    const f4* trfv = (const f4*)(trf + vox_i * 3);
    f4 t0 = trfv[0], t1 = trfv[1], t2 = trfv[2];

    // ---- stage vol tile into LDS (16B async, bits-2-4 z-XOR swizzle) ----
    // slot = 16B unit; row = slot>>3 (one z-row = 8 slots); dest is linear in
    // slot (wave-uniform base + lane*16B); source z inverse-swizzled.
    {
        const float* gbase = vb + ((size_t)(lox * NYD + loy) * NZD + loz);
#pragma unroll
        for (int it = 0; it < 5; ++it) {
            int slot = it * 512 + t;
            if (slot < NSLOT) {          // masked lanes are a contiguous suffix
                int row = slot >> 3;
                int zg  = (slot & 7) << 2;
                int yi  = row % LYT;
                int xi  = row / LYT;
                int sz  = zg ^ ((yi & 7) << 2);   // involution, 16B-preserving
                const float* g = gbase + (size_t)xi * (NYD * NZD) + yi * NZD + sz;
                __builtin_amdgcn_global_load_lds(
                    (const __attribute__((address_space(1))) void*)g,
                    (__attribute__((address_space(3))) void*)&tile[slot * 4],
                    16, 0, 0);
            }
        }
    }
    __syncthreads();

    // ---- gather + trilinear blend, 4 voxels ----
    float dxa[4] = {t0.x, t0.w, t1.z, t2.y};
    float dya[4] = {t0.y, t1.x, t1.w, t2.z};
    float dza[4] = {t0.z, t1.y, t2.x, t2.w};

    float res[4];
#pragma unroll
    for (int j = 0; j < 4; ++j) {
        float lx = fminf(fmaxf((float)x + dxa[j], 0.0f), (float)(NXD - 1));
        float ly = fminf(fmaxf((float)y + dya[j], 0.0f), (float)(NYD - 1));
        float lz = fminf(fmaxf((float)(zb0 + j) + dza[j], 0.0f), (float)(NZD - 1));
        float fx = floorf(lx), fy = floorf(ly), fz = floorf(lz);
        int x0 = (int)fx, y0 = (int)fy, z0 = (int)fz;
        // lower-corner weights d1 = loc1 - loc (0 at clamped top border)
        float wx0 = fminf(fx + 1.0f, (float)(NXD - 1)) - lx;
        float wy0 = fminf(fy + 1.0f, (float)(NYD - 1)) - ly;
        float wz0 = fminf(fz + 1.0f, (float)(NZD - 1)) - lz;

        int ix = x0 - lox, iy = y0 - loy, iz = z0 - loz;
        bool ok = ((unsigned)ix <= LXT - 2) & ((unsigned)iy <= LYT - 2) &
                  ((unsigned)iz <= LZT - 2);
        int sx = ok ? ix : 0;            // safe LDS coords when !ok
        int sy = ok ? iy : 0;
        int sv = ok ? iz : 0;

        int base = (sx * LYT + sy) * LZT;
        int sw0 = (sy & 7) << 2;
        int sw1 = ((sy + 1) & 7) << 2;
        int A = base + (sv ^ sw0);                    // (y0, z0)
        int B = base + ((sv + 1) ^ sw0);              // (y0, z1)
        int C = base + LZT + (sv ^ sw1);              // (y1, z0)
        int D = base + LZT + ((sv + 1) ^ sw1);        // (y1, z1)

        float v000 = tile[A],              v001 = tile[B];
        float v010 = tile[C],              v011 = tile[D];
        float v100 = tile[A + LYT * LZT],  v101 = tile[B + LYT * LZT];
        float v110 = tile[C + LYT * LZT],  v111 = tile[D + LYT * LZT];

        if (!ok) {   // rare: sample outside staged window -> global gather
            int x1 = min(x0 + 1, NXD - 1);
            int y1 = min(y0 + 1, NYD - 1);
            int z1 = min(z0 + 1, NZD - 1);
            size_t o00 = (size_t)(x0 * NYD + y0) * NZD;
            size_t o01 = (size_t)(x0 * NYD + y1) * NZD;
            size_t o10 = (size_t)(x1 * NYD + y0) * NZD;
            size_t o11 = (size_t)(x1 * NYD + y1) * NZD;
            v000 = vb[o00 + z0]; v001 = vb[o00 + z1];
            v010 = vb[o01 + z0]; v011 = vb[o01 + z1];
            v100 = vb[o10 + z0]; v101 = vb[o10 + z1];
            v110 = vb[o11 + z0]; v111 = vb[o11 + z1];
        }

        float wx1 = 1.0f - wx0, wy1 = 1.0f - wy0, wz1 = 1.0f - wz0;
        res[j] = wx0 * (wy0 * (wz0 * v000 + wz1 * v001) +
                        wy1 * (wz0 * v010 + wz1 * v011)) +
                 wx1 * (wy0 * (wz0 * v100 + wz1 * v101) +
                        wy1 * (wz0 * v110 + wz1 * v111));
    }

    f4 o;
    o.x = res[0]; o.y = res[1]; o.z = res[2]; o.w = res[3];
    *(f4*)(out + vox_i) = o;
}

extern "C" void kernel_launch(void* const* d_in, const int* in_sizes, int n_in,
                              void* d_out, int out_size, void* d_ws, size_t ws_size,
                              hipStream_t stream) {
    const float* vol = (const float*)d_in[0];
    const float* trf = (const float*)d_in[1];
    float* out = (float*)d_out;

    warp3d_kernel<<<NBLOCKS, 512, 0, stream>>>(vol, trf, out);
}